// Round 11
// baseline (269.084 us; speedup 1.0000x reference)
//
#include <hip/hip_runtime.h>
#include <stdint.h>

// 3-layer GCN, gather-only aggregation off a per-node CSR.
// R10 = R9 (253us) + three cuts:
//  - layer2 fused into k_agg30's epilogue (8-lane shfl butterfly over the
//    h-fragments): aggh 25.6MB round-trip and k_layer2 launch eliminated.
//    Safe now: aggregation accumulators are fp64, epilogue math unchanged.
//  - k_bucket_csr scatters csr directly to global: block exclusively owns
//    its 36KB region -> lines fully dirty in its own L2, no amplification.
//  - k_bin at 512 threads (halved per-edge serial iterations).
// Build writes remain linear-in-time where regions are shared (k_bin).
// Packed edge = (src<<9)|(dst&511), src < 2^18. dim-30 intermediate p2 is
// bf16 64B rows; k_agg30 gathers via 8-lane groups x uint2.

#define CAP 9216    // bucket region capacity; mean 8184, sigma 90 -> +11 sigma
#define CHUNK 3200  // edges per k_bin block

__device__ __forceinline__ unsigned short f2bf(float f) {  // RNE, no NaN inputs
    unsigned u = __float_as_uint(f);
    unsigned r = ((u >> 16) & 1u) + 0x7FFFu;
    return (unsigned short)((u + r) >> 16);
}
__device__ __forceinline__ float bf2f(unsigned short h) {
    return __uint_as_float((unsigned)h << 16);
}

// Per-block int64-vs-int32 detect: int64 edge values < 2^18 => all high
// words zero; int32 data at those offsets is src values, ~surely nonzero.
__device__ __forceinline__ int detect64(const unsigned* ei, int* s_nz, int t) {
    unsigned v = ei[2 * t + 1];
    if (v != 0) atomicAdd(s_nz, 1);
    __syncthreads();
    return (*s_nz == 0);
}

// Fused binning with local counting sort and coalesced copy-out. 512 thr.
__global__ __launch_bounds__(512) void k_bin(const void* ei, long long E,
                                             int* gcnt, unsigned* binned, int B) {
    __shared__ int hist[512];
    __shared__ int bnd[513];
    __shared__ int cursor[512];
    __shared__ int delta[512];
    __shared__ unsigned sv[CHUNK];
    __shared__ unsigned short sb[CHUNK];
    __shared__ int s_nz;
    int t = threadIdx.x, blk = blockIdx.x;
    if (t == 0) s_nz = 0;
    hist[t] = 0;
    __syncthreads();
    int f = detect64((const unsigned*)ei, &s_nz, t);
    long long s = (long long)blk * CHUNK, e = min(E, s + CHUNK);
    if (f) {
        const long long* p = (const long long*)ei;
        for (long long i = s + t; i < e; i += 512)
            atomicAdd(&hist[((int)p[E + i]) >> 9], 1);
    } else {
        const int* p = (const int*)ei;
        for (long long i = s + t; i < e; i += 512)
            atomicAdd(&hist[p[E + i] >> 9], 1);
    }
    __syncthreads();
    // exclusive scan over 512 buckets (1 per thread)
    int c = hist[t];
    int run = c;
    bnd[t] = c;  // reuse as scan array
    __syncthreads();
    for (int off = 1; off < 512; off <<= 1) {
        int add = (t >= off) ? bnd[t - off] : 0;
        __syncthreads();
        bnd[t] += add;
        __syncthreads();
    }
    int ex = bnd[t] - c;
    __syncthreads();
    bnd[t] = ex;
    cursor[t] = ex;
    if (t == 511) bnd[512] = ex + c;
    {
        int claim = c ? atomicAdd(&gcnt[t], c) : 0;
        delta[t] = t * CAP + claim - ex;
    }
    (void)run;
    __syncthreads();
    // scatter into LDS (sorted by bucket), remember bucket id
    if (f) {
        const long long* p = (const long long*)ei;
        for (long long i = s + t; i < e; i += 512) {
            int sval = (int)p[i], dv = (int)p[E + i];
            int b = dv >> 9;
            int pos = atomicAdd(&cursor[b], 1);
            sv[pos] = ((unsigned)sval << 9) | (unsigned)(dv & 511);
            sb[pos] = (unsigned short)b;
        }
    } else {
        const int* p = (const int*)ei;
        for (long long i = s + t; i < e; i += 512) {
            int sval = p[i], dv = p[E + i];
            int b = dv >> 9;
            int pos = atomicAdd(&cursor[b], 1);
            sv[pos] = ((unsigned)sval << 9) | (unsigned)(dv & 511);
            sb[pos] = (unsigned short)b;
        }
    }
    __syncthreads();
    // linear copy-out (consecutive threads -> consecutive addresses)
    int total = bnd[512];
    for (int i = t; i < total; i += 512)
        binned[delta[sb[i]] + i] = sv[i];
}

// Per-bucket counting sort by local node, scattering csr DIRECTLY to the
// block-owned global region. Also iptr2, dinv, p1 = x*dinv.
__global__ __launch_bounds__(512) void k_bucket_csr(
        const unsigned* binned, const int* gcnt, const float* x, int2* iptr2,
        float* dinv, float2* p1, int* csr, int n) {
    __shared__ int cur[512];
    __shared__ int sh[512];
    int t = threadIdx.x, b = blockIdx.x;
    cur[t] = 0;
    __syncthreads();
    int cnt = gcnt[b];
    const unsigned* bp = binned + (size_t)b * CAP;
    for (int i = t; i < cnt; i += 512)
        atomicAdd(&cur[bp[i] & 511u], 1);
    __syncthreads();
    int c = cur[t];
    sh[t] = c;
    __syncthreads();
    for (int off = 1; off < 512; off <<= 1) {
        int add = (t >= off) ? sh[t - off] : 0;
        __syncthreads();
        sh[t] += add;
        __syncthreads();
    }
    int ex = sh[t] - c;  // exclusive prefix
    int gbase = b * CAP;
    cur[t] = gbase + ex;  // global cursor
    int node = b * 512 + t;
    if (node < n) {
        iptr2[node] = make_int2(gbase + ex, gbase + ex + c);
        float dg = (float)(c + 1);  // +1 self loop
        float r = rsqrtf(dg);
        r = r * (1.5f - 0.5f * dg * r * r);  // Newton refine
        dinv[node] = r;
        p1[node] = make_float2(x[2 * node] * r, x[2 * node + 1] * r);
    }
    __syncthreads();
    for (int i = t; i < cnt; i += 512) {
        unsigned p = bp[i];
        int pos = atomicAdd(&cur[p & 511u], 1);
        csr[pos] = (int)(p >> 9);
    }
}

// Fused: aggx = A_hat x (dim2, x8 unroll, fp64 acc);
// p2 = bf16(relu(aggx@W1+b1)*dinv), 64B rows (32 ushorts, 2 zero pads).
__global__ void k_agg2_l1(const float2* p1, const int2* iptr2, const int* csr,
                          const float* dinv, const float* W1, const float* b1,
                          float2* aggx, unsigned short* p2, int n) {
    int v = blockIdx.x * 256 + threadIdx.x;
    if (v >= n) return;
    float2 a0 = p1[v];
    double dax = a0.x, day = a0.y;
    int2 se = iptr2[v];
    int s = se.x, e = se.y;
    int i = s;
    for (; i + 7 < e; i += 8) {
        int u0 = csr[i], u1 = csr[i + 1], u2 = csr[i + 2], u3 = csr[i + 3];
        int u4 = csr[i + 4], u5 = csr[i + 5], u6 = csr[i + 6], u7 = csr[i + 7];
        float2 q0 = p1[u0], q1 = p1[u1], q2 = p1[u2], q3 = p1[u3];
        float2 q4 = p1[u4], q5 = p1[u5], q6 = p1[u6], q7 = p1[u7];
        dax += ((double)q0.x + q1.x) + ((double)q2.x + q3.x) +
               ((double)q4.x + q5.x) + ((double)q6.x + q7.x);
        day += ((double)q0.y + q1.y) + ((double)q2.y + q3.y) +
               ((double)q4.y + q5.y) + ((double)q6.y + q7.y);
    }
    for (; i < e; i++) {
        float2 q = p1[csr[i]];
        dax += (double)q.x; day += (double)q.y;
    }
    float r = dinv[v];
    float ax = (float)(dax * (double)r), ay = (float)(day * (double)r);
    aggx[v] = make_float2(ax, ay);
    __align__(16) unsigned short ob[32];
#pragma unroll
    for (int j = 0; j < 30; j++)
        ob[j] = f2bf(fmaxf(fmaf(ax, W1[j], fmaf(ay, W1[30 + j], b1[j])), 0.f) * r);
    ob[30] = 0; ob[31] = 0;
    uint4* d4 = (uint4*)(p2 + (size_t)v * 32);
    const uint4* s4 = (const uint4*)ob;
#pragma unroll
    for (int k = 0; k < 4; k++) d4[k] = s4[k];
}

// Dim-30 aggregation (8-lane group per node, uint2 = 4 bf16 per lane,
// x8-unrolled independent 64B gathers, fp64 acc) FUSED with layer2:
// lane l holds h-cols 4l..4l+3; part[j] = sum_k h_k W2[k][j] is butterfly-
// reduced across the 8 lanes; then h2=relu(part+aggx@W2[30:]+b2),
// p3 = ([h2,x]@W3)*dinv.
__global__ void k_agg30_l2(const uint2* p2u, const int2* iptr2, const int* csr,
                           const float* dinv, const float2* aggx,
                           const float* x, const float* W2, const float* W3,
                           const float* b2, float* p3, int n) {
    __shared__ float W2s[960];
    __shared__ float W3s[32];
    __shared__ float b2s[30];
    int t = threadIdx.x;
    for (int i = t; i < 960; i += 256) W2s[i] = W2[i];
    if (t < 32) W3s[t] = W3[t];
    if (t < 30) b2s[t] = b2[t];
    __syncthreads();
    int g = blockIdx.x * 32 + (t >> 3);
    int l = t & 7;
    if (g >= n) return;
    uint2 w = p2u[(size_t)g * 8 + l];  // self loop (pads zero)
    double a0 = (double)bf2f((unsigned short)(w.x & 0xFFFFu));
    double a1 = (double)bf2f((unsigned short)(w.x >> 16));
    double a2 = (double)bf2f((unsigned short)(w.y & 0xFFFFu));
    double a3 = (double)bf2f((unsigned short)(w.y >> 16));
    int2 se = iptr2[g];
    int s = se.x, e = se.y;
    int i = s;
    for (; i + 7 < e; i += 8) {
        int u0 = csr[i], u1 = csr[i + 1], u2 = csr[i + 2], u3 = csr[i + 3];
        int u4 = csr[i + 4], u5 = csr[i + 5], u6 = csr[i + 6], u7 = csr[i + 7];
        uint2 w0 = p2u[(size_t)u0 * 8 + l];
        uint2 w1 = p2u[(size_t)u1 * 8 + l];
        uint2 w2 = p2u[(size_t)u2 * 8 + l];
        uint2 w3 = p2u[(size_t)u3 * 8 + l];
        uint2 w4 = p2u[(size_t)u4 * 8 + l];
        uint2 w5 = p2u[(size_t)u5 * 8 + l];
        uint2 w6 = p2u[(size_t)u6 * 8 + l];
        uint2 w7 = p2u[(size_t)u7 * 8 + l];
        a0 += ((double)bf2f((unsigned short)(w0.x & 0xFFFFu)) + bf2f((unsigned short)(w1.x & 0xFFFFu))) +
              ((double)bf2f((unsigned short)(w2.x & 0xFFFFu)) + bf2f((unsigned short)(w3.x & 0xFFFFu))) +
              ((double)bf2f((unsigned short)(w4.x & 0xFFFFu)) + bf2f((unsigned short)(w5.x & 0xFFFFu))) +
              ((double)bf2f((unsigned short)(w6.x & 0xFFFFu)) + bf2f((unsigned short)(w7.x & 0xFFFFu)));
        a1 += ((double)bf2f((unsigned short)(w0.x >> 16)) + bf2f((unsigned short)(w1.x >> 16))) +
              ((double)bf2f((unsigned short)(w2.x >> 16)) + bf2f((unsigned short)(w3.x >> 16))) +
              ((double)bf2f((unsigned short)(w4.x >> 16)) + bf2f((unsigned short)(w5.x >> 16))) +
              ((double)bf2f((unsigned short)(w6.x >> 16)) + bf2f((unsigned short)(w7.x >> 16)));
        a2 += ((double)bf2f((unsigned short)(w0.y & 0xFFFFu)) + bf2f((unsigned short)(w1.y & 0xFFFFu))) +
              ((double)bf2f((unsigned short)(w2.y & 0xFFFFu)) + bf2f((unsigned short)(w3.y & 0xFFFFu))) +
              ((double)bf2f((unsigned short)(w4.y & 0xFFFFu)) + bf2f((unsigned short)(w5.y & 0xFFFFu))) +
              ((double)bf2f((unsigned short)(w6.y & 0xFFFFu)) + bf2f((unsigned short)(w7.y & 0xFFFFu)));
        a3 += ((double)bf2f((unsigned short)(w0.y >> 16)) + bf2f((unsigned short)(w1.y >> 16))) +
              ((double)bf2f((unsigned short)(w2.y >> 16)) + bf2f((unsigned short)(w3.y >> 16))) +
              ((double)bf2f((unsigned short)(w4.y >> 16)) + bf2f((unsigned short)(w5.y >> 16))) +
              ((double)bf2f((unsigned short)(w6.y >> 16)) + bf2f((unsigned short)(w7.y >> 16)));
    }
    for (; i < e; i++) {
        uint2 wv = p2u[(size_t)csr[i] * 8 + l];
        a0 += (double)bf2f((unsigned short)(wv.x & 0xFFFFu));
        a1 += (double)bf2f((unsigned short)(wv.x >> 16));
        a2 += (double)bf2f((unsigned short)(wv.y & 0xFFFFu));
        a3 += (double)bf2f((unsigned short)(wv.y >> 16));
    }
    double rd = (double)dinv[g];
    float h0 = (float)(a0 * rd), h1 = (float)(a1 * rd);
    float h2 = (float)(a2 * rd), h3 = (float)(a3 * rd);
    // lane 7: h2,h3 are cols 30,31 -> zero sums -> contribute 0 below.
    int k0 = 4 * l;
    float part[30];
#pragma unroll
    for (int j = 0; j < 30; j++) {
        float sj = h0 * W2s[k0 * 30 + j];
        sj = fmaf(h1, W2s[(k0 + 1) * 30 + j], sj);
        sj = fmaf(h2, W2s[(k0 + 2) * 30 + j], sj);
        sj = fmaf(h3, W2s[(k0 + 3) * 30 + j], sj);
        part[j] = sj;
    }
#pragma unroll
    for (int m = 1; m < 8; m <<= 1) {
#pragma unroll
        for (int j = 0; j < 30; j++)
            part[j] += __shfl_xor(part[j], m, 64);
    }
    // all 8 lanes now hold the full sum; compute s3 redundantly, lane 0 writes
    float2 a = aggx[g];
    float s3 = 0.f;
#pragma unroll
    for (int j = 0; j < 30; j++) {
        float acc = part[j] + b2s[j];
        acc = fmaf(a.x, W2s[900 + j], acc);
        acc = fmaf(a.y, W2s[930 + j], acc);
        s3 = fmaf(fmaxf(acc, 0.f), W3s[j], s3);
    }
    s3 = fmaf(x[2 * g], W3s[30], s3);
    s3 = fmaf(x[2 * g + 1], W3s[31], s3);
    if (l == 0) p3[g] = s3 * (float)rd;
}

// out_v = dinv_v * (p3_v + sum p3_u) + b3   (dim 1, x8 unroll, fp64 acc)
__global__ void k_agg1(const float* p3, const int2* iptr2, const int* csr,
                       const float* dinv, const float* b3, float* out, int n) {
    int v = blockIdx.x * 256 + threadIdx.x;
    if (v >= n) return;
    double acc = (double)p3[v];
    int2 se = iptr2[v];
    int s = se.x, e = se.y;
    int i = s;
    for (; i + 7 < e; i += 8) {
        int u0 = csr[i], u1 = csr[i + 1], u2 = csr[i + 2], u3 = csr[i + 3];
        int u4 = csr[i + 4], u5 = csr[i + 5], u6 = csr[i + 6], u7 = csr[i + 7];
        float f0 = p3[u0], f1 = p3[u1], f2 = p3[u2], f3 = p3[u3];
        float f4 = p3[u4], f5 = p3[u5], f6 = p3[u6], f7 = p3[u7];
        acc += ((double)f0 + f1) + ((double)f2 + f3) +
               ((double)f4 + f5) + ((double)f6 + f7);
    }
    for (; i < e; i++) acc += (double)p3[csr[i]];
    out[v] = (float)(acc * (double)dinv[v] + (double)b3[0]);
}

extern "C" void kernel_launch(void* const* d_in, const int* in_sizes, int n_in,
                              void* d_out, int out_size, void* d_ws, size_t ws_size,
                              hipStream_t stream) {
    const float* x  = (const float*)d_in[0];
    const void*  ei = d_in[1];
    const float* W1 = (const float*)d_in[2];
    const float* b1 = (const float*)d_in[3];
    const float* W2 = (const float*)d_in[4];
    const float* b2 = (const float*)d_in[5];
    const float* W3 = (const float*)d_in[6];
    const float* b3 = (const float*)d_in[7];
    float* out = (float*)d_out;
    const int n = in_sizes[0] / 2;
    const long long E = in_sizes[1] / 2;
    const int B = (n + 511) / 512;  // dst buckets of 512 nodes (<=512 buckets)

    char* w = (char*)d_ws;
    auto alloc = [&](size_t b) { void* p = (void*)w; w += (b + 255) & ~(size_t)255; return p; };
    int*            gcnt   = (int*)alloc(512 * 4);
    unsigned*       binned = (unsigned*)alloc((size_t)B * CAP * 4);
    int*            csr    = (int*)alloc((size_t)B * CAP * 4);
    int2*           iptr2  = (int2*)alloc((size_t)n * 8);
    float*          dinv   = (float*)alloc((size_t)n * 4);
    float2*         p1     = (float2*)alloc((size_t)n * 8);
    float2*         aggx   = (float2*)alloc((size_t)n * 8);
    unsigned short* p2     = (unsigned short*)alloc((size_t)n * 32 * 2);
    float*          p3     = (float*)alloc((size_t)n * 4);

    int nblocks = (n + 255) / 256;
    int nbin = (int)((E + CHUNK - 1) / CHUNK);

    hipMemsetAsync(gcnt, 0, 512 * 4, stream);
    k_bin<<<nbin, 512, 0, stream>>>(ei, E, gcnt, binned, B);
    k_bucket_csr<<<B, 512, 0, stream>>>(binned, gcnt, x, iptr2, dinv, p1, csr, n);
    k_agg2_l1<<<nblocks, 256, 0, stream>>>(p1, iptr2, csr, dinv, W1, b1, aggx, p2, n);
    k_agg30_l2<<<(n + 31) / 32, 256, 0, stream>>>((const uint2*)p2, iptr2, csr,
                                                  dinv, aggx, x, W2, W3, b2, p3, n);
    k_agg1<<<nblocks, 256, 0, stream>>>(p3, iptr2, csr, dinv, b3, out, n);
}

// Round 12
// 254.332 us; speedup vs baseline: 1.0580x; 1.0580x over previous
//
#include <hip/hip_runtime.h>
#include <stdint.h>

// 3-layer GCN, gather-only aggregation off a per-node CSR.
// R11 = best-of: R10's build kernels (512-thr k_bin, direct-scatter
// k_bucket_csr: together ~10us faster than R9's) + R9's proven split
// aggregation (k_agg30 32-VGPR/68%-occ + k_layer2 LDS-staged; R10's fused
// epilogue cost +25us in VGPR pressure & 90 shfl/node -> reverted).
// Packed edge = (src<<9)|(dst&511), src < 2^18. Aggregation accumulators
// FP64 (order-independent accuracy; CSR order nondeterministic). dim-30
// intermediates bf16 64B rows; k_agg30 = 8-lane groups x uint2.

#define CAP 9216    // bucket region capacity; mean 8184, sigma 90 -> +11 sigma
#define CHUNK 3200  // edges per k_bin block

__device__ __forceinline__ unsigned short f2bf(float f) {  // RNE, no NaN inputs
    unsigned u = __float_as_uint(f);
    unsigned r = ((u >> 16) & 1u) + 0x7FFFu;
    return (unsigned short)((u + r) >> 16);
}
__device__ __forceinline__ float bf2f(unsigned short h) {
    return __uint_as_float((unsigned)h << 16);
}

// Per-block int64-vs-int32 detect: int64 edge values < 2^18 => all high
// words zero; int32 data at those offsets is src values, ~surely nonzero.
__device__ __forceinline__ int detect64(const unsigned* ei, int* s_nz, int t) {
    unsigned v = ei[2 * t + 1];
    if (v != 0) atomicAdd(s_nz, 1);
    __syncthreads();
    return (*s_nz == 0);
}

// Fused binning with local counting sort and coalesced copy-out. 512 thr.
__global__ __launch_bounds__(512) void k_bin(const void* ei, long long E,
                                             int* gcnt, unsigned* binned, int B) {
    __shared__ int hist[512];
    __shared__ int bnd[513];
    __shared__ int cursor[512];
    __shared__ int delta[512];
    __shared__ unsigned sv[CHUNK];
    __shared__ unsigned short sb[CHUNK];
    __shared__ int s_nz;
    int t = threadIdx.x, blk = blockIdx.x;
    if (t == 0) s_nz = 0;
    hist[t] = 0;
    __syncthreads();
    int f = detect64((const unsigned*)ei, &s_nz, t);
    long long s = (long long)blk * CHUNK, e = min(E, s + CHUNK);
    if (f) {
        const long long* p = (const long long*)ei;
        for (long long i = s + t; i < e; i += 512)
            atomicAdd(&hist[((int)p[E + i]) >> 9], 1);
    } else {
        const int* p = (const int*)ei;
        for (long long i = s + t; i < e; i += 512)
            atomicAdd(&hist[p[E + i] >> 9], 1);
    }
    __syncthreads();
    // exclusive scan over 512 buckets (1 per thread)
    int c = hist[t];
    bnd[t] = c;  // reuse as scan array
    __syncthreads();
    for (int off = 1; off < 512; off <<= 1) {
        int add = (t >= off) ? bnd[t - off] : 0;
        __syncthreads();
        bnd[t] += add;
        __syncthreads();
    }
    int ex = bnd[t] - c;
    __syncthreads();
    bnd[t] = ex;
    cursor[t] = ex;
    if (t == 511) bnd[512] = ex + c;
    {
        int claim = c ? atomicAdd(&gcnt[t], c) : 0;
        delta[t] = t * CAP + claim - ex;
    }
    __syncthreads();
    // scatter into LDS (sorted by bucket), remember bucket id
    if (f) {
        const long long* p = (const long long*)ei;
        for (long long i = s + t; i < e; i += 512) {
            int sval = (int)p[i], dv = (int)p[E + i];
            int b = dv >> 9;
            int pos = atomicAdd(&cursor[b], 1);
            sv[pos] = ((unsigned)sval << 9) | (unsigned)(dv & 511);
            sb[pos] = (unsigned short)b;
        }
    } else {
        const int* p = (const int*)ei;
        for (long long i = s + t; i < e; i += 512) {
            int sval = p[i], dv = p[E + i];
            int b = dv >> 9;
            int pos = atomicAdd(&cursor[b], 1);
            sv[pos] = ((unsigned)sval << 9) | (unsigned)(dv & 511);
            sb[pos] = (unsigned short)b;
        }
    }
    __syncthreads();
    // linear copy-out (consecutive threads -> consecutive addresses)
    int total = bnd[512];
    for (int i = t; i < total; i += 512)
        binned[delta[sb[i]] + i] = sv[i];
}

// Per-bucket counting sort by local node, scattering csr DIRECTLY to the
// block-owned global region. Also iptr2, dinv, p1 = x*dinv.
__global__ __launch_bounds__(512) void k_bucket_csr(
        const unsigned* binned, const int* gcnt, const float* x, int2* iptr2,
        float* dinv, float2* p1, int* csr, int n) {
    __shared__ int cur[512];
    __shared__ int sh[512];
    int t = threadIdx.x, b = blockIdx.x;
    cur[t] = 0;
    __syncthreads();
    int cnt = gcnt[b];
    const unsigned* bp = binned + (size_t)b * CAP;
    for (int i = t; i < cnt; i += 512)
        atomicAdd(&cur[bp[i] & 511u], 1);
    __syncthreads();
    int c = cur[t];
    sh[t] = c;
    __syncthreads();
    for (int off = 1; off < 512; off <<= 1) {
        int add = (t >= off) ? sh[t - off] : 0;
        __syncthreads();
        sh[t] += add;
        __syncthreads();
    }
    int ex = sh[t] - c;  // exclusive prefix
    int gbase = b * CAP;
    cur[t] = gbase + ex;  // global cursor
    int node = b * 512 + t;
    if (node < n) {
        iptr2[node] = make_int2(gbase + ex, gbase + ex + c);
        float dg = (float)(c + 1);  // +1 self loop
        float r = rsqrtf(dg);
        r = r * (1.5f - 0.5f * dg * r * r);  // Newton refine
        dinv[node] = r;
        p1[node] = make_float2(x[2 * node] * r, x[2 * node + 1] * r);
    }
    __syncthreads();
    for (int i = t; i < cnt; i += 512) {
        unsigned p = bp[i];
        int pos = atomicAdd(&cur[p & 511u], 1);
        csr[pos] = (int)(p >> 9);
    }
}

// Fused: aggx = A_hat x (dim2, x8 unroll, fp64 acc);
// p2 = bf16(relu(aggx@W1+b1)*dinv), 64B rows (32 ushorts, 2 zero pads).
__global__ void k_agg2_l1(const float2* p1, const int2* iptr2, const int* csr,
                          const float* dinv, const float* W1, const float* b1,
                          float2* aggx, unsigned short* p2, int n) {
    int v = blockIdx.x * 256 + threadIdx.x;
    if (v >= n) return;
    float2 a0 = p1[v];
    double dax = a0.x, day = a0.y;
    int2 se = iptr2[v];
    int s = se.x, e = se.y;
    int i = s;
    for (; i + 7 < e; i += 8) {
        int u0 = csr[i], u1 = csr[i + 1], u2 = csr[i + 2], u3 = csr[i + 3];
        int u4 = csr[i + 4], u5 = csr[i + 5], u6 = csr[i + 6], u7 = csr[i + 7];
        float2 q0 = p1[u0], q1 = p1[u1], q2 = p1[u2], q3 = p1[u3];
        float2 q4 = p1[u4], q5 = p1[u5], q6 = p1[u6], q7 = p1[u7];
        dax += ((double)q0.x + q1.x) + ((double)q2.x + q3.x) +
               ((double)q4.x + q5.x) + ((double)q6.x + q7.x);
        day += ((double)q0.y + q1.y) + ((double)q2.y + q3.y) +
               ((double)q4.y + q5.y) + ((double)q6.y + q7.y);
    }
    for (; i < e; i++) {
        float2 q = p1[csr[i]];
        dax += (double)q.x; day += (double)q.y;
    }
    float r = dinv[v];
    float ax = (float)(dax * (double)r), ay = (float)(day * (double)r);
    aggx[v] = make_float2(ax, ay);
    __align__(16) unsigned short ob[32];
#pragma unroll
    for (int j = 0; j < 30; j++)
        ob[j] = f2bf(fmaxf(fmaf(ax, W1[j], fmaf(ay, W1[30 + j], b1[j])), 0.f) * r);
    ob[30] = 0; ob[31] = 0;
    uint4* d4 = (uint4*)(p2 + (size_t)v * 32);
    const uint4* s4 = (const uint4*)ob;
#pragma unroll
    for (int k = 0; k < 4; k++) d4[k] = s4[k];
}

// Dim-30 aggregation: 8-lane group per node, each lane a uint2 (4 bf16,
// 64B/row/group), x8-unrolled independent gathers, fp64 accumulators.
__global__ void k_agg30(const uint2* p2u, const int2* iptr2,
                        const int* csr, const float* dinv,
                        uint2* agghu, int n) {
    int t = threadIdx.x;
    int g = blockIdx.x * 32 + (t >> 3);
    int l = t & 7;
    if (g >= n) return;
    uint2 w = p2u[(size_t)g * 8 + l];  // self loop (pads zero)
    double a0 = (double)bf2f((unsigned short)(w.x & 0xFFFFu));
    double a1 = (double)bf2f((unsigned short)(w.x >> 16));
    double a2 = (double)bf2f((unsigned short)(w.y & 0xFFFFu));
    double a3 = (double)bf2f((unsigned short)(w.y >> 16));
    int2 se = iptr2[g];
    int s = se.x, e = se.y;
    int i = s;
    for (; i + 7 < e; i += 8) {
        int u0 = csr[i], u1 = csr[i + 1], u2 = csr[i + 2], u3 = csr[i + 3];
        int u4 = csr[i + 4], u5 = csr[i + 5], u6 = csr[i + 6], u7 = csr[i + 7];
        uint2 w0 = p2u[(size_t)u0 * 8 + l];
        uint2 w1 = p2u[(size_t)u1 * 8 + l];
        uint2 w2 = p2u[(size_t)u2 * 8 + l];
        uint2 w3 = p2u[(size_t)u3 * 8 + l];
        uint2 w4 = p2u[(size_t)u4 * 8 + l];
        uint2 w5 = p2u[(size_t)u5 * 8 + l];
        uint2 w6 = p2u[(size_t)u6 * 8 + l];
        uint2 w7 = p2u[(size_t)u7 * 8 + l];
        a0 += ((double)bf2f((unsigned short)(w0.x & 0xFFFFu)) + bf2f((unsigned short)(w1.x & 0xFFFFu))) +
              ((double)bf2f((unsigned short)(w2.x & 0xFFFFu)) + bf2f((unsigned short)(w3.x & 0xFFFFu))) +
              ((double)bf2f((unsigned short)(w4.x & 0xFFFFu)) + bf2f((unsigned short)(w5.x & 0xFFFFu))) +
              ((double)bf2f((unsigned short)(w6.x & 0xFFFFu)) + bf2f((unsigned short)(w7.x & 0xFFFFu)));
        a1 += ((double)bf2f((unsigned short)(w0.x >> 16)) + bf2f((unsigned short)(w1.x >> 16))) +
              ((double)bf2f((unsigned short)(w2.x >> 16)) + bf2f((unsigned short)(w3.x >> 16))) +
              ((double)bf2f((unsigned short)(w4.x >> 16)) + bf2f((unsigned short)(w5.x >> 16))) +
              ((double)bf2f((unsigned short)(w6.x >> 16)) + bf2f((unsigned short)(w7.x >> 16)));
        a2 += ((double)bf2f((unsigned short)(w0.y & 0xFFFFu)) + bf2f((unsigned short)(w1.y & 0xFFFFu))) +
              ((double)bf2f((unsigned short)(w2.y & 0xFFFFu)) + bf2f((unsigned short)(w3.y & 0xFFFFu))) +
              ((double)bf2f((unsigned short)(w4.y & 0xFFFFu)) + bf2f((unsigned short)(w5.y & 0xFFFFu))) +
              ((double)bf2f((unsigned short)(w6.y & 0xFFFFu)) + bf2f((unsigned short)(w7.y & 0xFFFFu)));
        a3 += ((double)bf2f((unsigned short)(w0.y >> 16)) + bf2f((unsigned short)(w1.y >> 16))) +
              ((double)bf2f((unsigned short)(w2.y >> 16)) + bf2f((unsigned short)(w3.y >> 16))) +
              ((double)bf2f((unsigned short)(w4.y >> 16)) + bf2f((unsigned short)(w5.y >> 16))) +
              ((double)bf2f((unsigned short)(w6.y >> 16)) + bf2f((unsigned short)(w7.y >> 16)));
    }
    for (; i < e; i++) {
        uint2 wv = p2u[(size_t)csr[i] * 8 + l];
        a0 += (double)bf2f((unsigned short)(wv.x & 0xFFFFu));
        a1 += (double)bf2f((unsigned short)(wv.x >> 16));
        a2 += (double)bf2f((unsigned short)(wv.y & 0xFFFFu));
        a3 += (double)bf2f((unsigned short)(wv.y >> 16));
    }
    double r = (double)dinv[g];
    uint2 o;
    o.x = (unsigned)f2bf((float)(a0 * r)) | ((unsigned)f2bf((float)(a1 * r)) << 16);
    o.y = (unsigned)f2bf((float)(a2 * r)) | ((unsigned)f2bf((float)(a3 * r)) << 16);
    agghu[(size_t)g * 8 + l] = o;  // pads (cols 30,31) are zero-sums -> stay 0
}

// h2 = relu((Ah1)W2[:30] + (Ax)W2[30:] + b2); p3 = ([h2,x]@W3) * dinv.
// Block stages its 256 bf16 aggh rows through LDS (stride-17 uints).
__global__ void k_layer2(const unsigned short* aggh, const float2* aggx,
                         const float* x, const float* W2, const float* W3,
                         const float* b2, const float* dinv, float* p3, int n) {
    __shared__ float W2s[32 * 30];
    __shared__ float W3s[32];
    __shared__ float b2s[30];
    __shared__ unsigned hsh[256 * 17];
    int t = threadIdx.x;
    for (int i = t; i < 960; i += 256) W2s[i] = W2[i];
    if (t < 32) W3s[t] = W3[t];
    if (t < 30) b2s[t] = b2[t];
    const unsigned* ag = (const unsigned*)aggh + (size_t)blockIdx.x * 256 * 16;
    int rows = min(256, n - blockIdx.x * 256);
    for (int i = t; i < rows * 16; i += 256) {
        int rr = i >> 4, cc = i & 15;
        hsh[rr * 17 + cc] = ag[i];
    }
    __syncthreads();
    int v = blockIdx.x * 256 + t;
    if (v >= n) return;
    float2 a = aggx[v];
    float acc[30];
#pragma unroll
    for (int j = 0; j < 30; j++)
        acc[j] = fmaf(a.x, W2s[30 * 30 + j], fmaf(a.y, W2s[31 * 30 + j], b2s[j]));
#pragma unroll
    for (int kk = 0; kk < 15; kk++) {  // 30 values = 15 uint pairs
        unsigned pr = hsh[t * 17 + kk];
        float h0 = bf2f((unsigned short)(pr & 0xFFFFu));
        float h1v = bf2f((unsigned short)(pr >> 16));
#pragma unroll
        for (int j = 0; j < 30; j++)
            acc[j] = fmaf(h0, W2s[(2 * kk) * 30 + j], acc[j]);
#pragma unroll
        for (int j = 0; j < 30; j++)
            acc[j] = fmaf(h1v, W2s[(2 * kk + 1) * 30 + j], acc[j]);
    }
    float s3 = 0.f;
#pragma unroll
    for (int j = 0; j < 30; j++) s3 = fmaf(fmaxf(acc[j], 0.f), W3s[j], s3);
    s3 = fmaf(x[2 * v], W3s[30], s3);
    s3 = fmaf(x[2 * v + 1], W3s[31], s3);
    p3[v] = s3 * dinv[v];
}

// out_v = dinv_v * (p3_v + sum p3_u) + b3   (dim 1, x8 unroll, fp64 acc)
__global__ void k_agg1(const float* p3, const int2* iptr2, const int* csr,
                       const float* dinv, const float* b3, float* out, int n) {
    int v = blockIdx.x * 256 + threadIdx.x;
    if (v >= n) return;
    double acc = (double)p3[v];
    int2 se = iptr2[v];
    int s = se.x, e = se.y;
    int i = s;
    for (; i + 7 < e; i += 8) {
        int u0 = csr[i], u1 = csr[i + 1], u2 = csr[i + 2], u3 = csr[i + 3];
        int u4 = csr[i + 4], u5 = csr[i + 5], u6 = csr[i + 6], u7 = csr[i + 7];
        float f0 = p3[u0], f1 = p3[u1], f2 = p3[u2], f3 = p3[u3];
        float f4 = p3[u4], f5 = p3[u5], f6 = p3[u6], f7 = p3[u7];
        acc += ((double)f0 + f1) + ((double)f2 + f3) +
               ((double)f4 + f5) + ((double)f6 + f7);
    }
    for (; i < e; i++) acc += (double)p3[csr[i]];
    out[v] = (float)(acc * (double)dinv[v] + (double)b3[0]);
}

extern "C" void kernel_launch(void* const* d_in, const int* in_sizes, int n_in,
                              void* d_out, int out_size, void* d_ws, size_t ws_size,
                              hipStream_t stream) {
    const float* x  = (const float*)d_in[0];
    const void*  ei = d_in[1];
    const float* W1 = (const float*)d_in[2];
    const float* b1 = (const float*)d_in[3];
    const float* W2 = (const float*)d_in[4];
    const float* b2 = (const float*)d_in[5];
    const float* W3 = (const float*)d_in[6];
    const float* b3 = (const float*)d_in[7];
    float* out = (float*)d_out;
    const int n = in_sizes[0] / 2;
    const long long E = in_sizes[1] / 2;
    const int B = (n + 511) / 512;  // dst buckets of 512 nodes (<=512 buckets)

    char* w = (char*)d_ws;
    auto alloc = [&](size_t b) { void* p = (void*)w; w += (b + 255) & ~(size_t)255; return p; };
    int*            gcnt   = (int*)alloc(512 * 4);
    unsigned*       binned = (unsigned*)alloc((size_t)B * CAP * 4);
    int*            csr    = (int*)alloc((size_t)B * CAP * 4);
    int2*           iptr2  = (int2*)alloc((size_t)n * 8);
    float*          dinv   = (float*)alloc((size_t)n * 4);
    float2*         p1     = (float2*)alloc((size_t)n * 8);
    float2*         aggx   = (float2*)alloc((size_t)n * 8);
    unsigned short* p2     = (unsigned short*)alloc((size_t)n * 32 * 2);
    unsigned short* aggh   = (unsigned short*)alloc((size_t)n * 32 * 2);
    float*          p3     = (float*)alloc((size_t)n * 4);

    int nblocks = (n + 255) / 256;
    int nbin = (int)((E + CHUNK - 1) / CHUNK);

    hipMemsetAsync(gcnt, 0, 512 * 4, stream);
    k_bin<<<nbin, 512, 0, stream>>>(ei, E, gcnt, binned, B);
    k_bucket_csr<<<B, 512, 0, stream>>>(binned, gcnt, x, iptr2, dinv, p1, csr, n);
    k_agg2_l1<<<nblocks, 256, 0, stream>>>(p1, iptr2, csr, dinv, W1, b1, aggx, p2, n);
    k_agg30<<<(n + 31) / 32, 256, 0, stream>>>((const uint2*)p2, iptr2, csr, dinv,
                                               (uint2*)aggh, n);
    k_layer2<<<nblocks, 256, 0, stream>>>(aggh, aggx, x, W2, W3, b2, dinv, p3, n);
    k_agg1<<<nblocks, 256, 0, stream>>>(p3, iptr2, csr, dinv, b3, out, n);
}

// Round 13
// 243.748 us; speedup vs baseline: 1.1039x; 1.0434x over previous
//
#include <hip/hip_runtime.h>
#include <stdint.h>

// 3-layer GCN, gather-only aggregation off a per-node CSR.
// R12 = R11 aggregation (proven: k_agg30 54us @70% occ, split k_layer2)
// + build-kernel de-serialization:
//  k_bin: CHUNK 6400 (500 blocks; per-block scan/claim amortized 2x, longer
//    write runs), wave-shuffle scan (6 shfl rounds + 1 barrier vs 18
//    barriers of Hillis-Steele).
//  k_bucket_csr: 1024 threads (hist/scatter serial iterations halved),
//    shuffle scan over the 512 node counters.
// Packed edge = (src<<9)|(dst&511), src < 2^18. Aggregation accumulators
// FP64 (order-independent accuracy; CSR order nondeterministic). dim-30
// intermediates bf16 64B rows; k_agg30 = 8-lane groups x uint2.

#define CAP 9216    // bucket region capacity; mean 8184, sigma 90 -> +11 sigma
#define CHUNK 6400  // edges per k_bin block

__device__ __forceinline__ unsigned short f2bf(float f) {  // RNE, no NaN inputs
    unsigned u = __float_as_uint(f);
    unsigned r = ((u >> 16) & 1u) + 0x7FFFu;
    return (unsigned short)((u + r) >> 16);
}
__device__ __forceinline__ float bf2f(unsigned short h) {
    return __uint_as_float((unsigned)h << 16);
}

// Per-block int64-vs-int32 detect: int64 edge values < 2^18 => all high
// words zero; int32 data at those offsets is src values, ~surely nonzero.
__device__ __forceinline__ int detect64(const unsigned* ei, int* s_nz, int t) {
    unsigned v = ei[2 * (t & 255) + 1];
    if (v != 0) atomicAdd(s_nz, 1);
    __syncthreads();
    return (*s_nz == 0);
}

// Fused binning with local counting sort and coalesced copy-out. 512 thr.
__global__ __launch_bounds__(512) void k_bin(const void* ei, long long E,
                                             int* gcnt, unsigned* binned, int B) {
    __shared__ int cursor[512];
    __shared__ int delta[512];
    __shared__ int wsum[8];
    __shared__ int s_total;
    __shared__ unsigned sv[CHUNK];
    __shared__ unsigned short sb[CHUNK];
    __shared__ int s_nz;
    int t = threadIdx.x, blk = blockIdx.x;
    if (t == 0) s_nz = 0;
    cursor[t] = 0;
    __syncthreads();
    int f = detect64((const unsigned*)ei, &s_nz, t);
    long long s = (long long)blk * CHUNK, e = min(E, s + CHUNK);
    if (f) {
        const long long* p = (const long long*)ei;
        for (long long i = s + t; i < e; i += 512)
            atomicAdd(&cursor[((int)p[E + i]) >> 9], 1);
    } else {
        const int* p = (const int*)ei;
        for (long long i = s + t; i < e; i += 512)
            atomicAdd(&cursor[p[E + i] >> 9], 1);
    }
    __syncthreads();
    // exclusive scan over 512 counts: wave shuffle scan + cross-wave offsets
    int c = cursor[t];
    int lane = t & 63, wid = t >> 6;
    int inc = c;
#pragma unroll
    for (int off = 1; off < 64; off <<= 1) {
        int up = __shfl_up(inc, off, 64);
        if (lane >= off) inc += up;
    }
    if (lane == 63) wsum[wid] = inc;
    __syncthreads();
    int base = 0;
    for (int k = 0; k < wid; k++) base += wsum[k];
    int ex = base + inc - c;
    if (t == 511) s_total = ex + c;
    int claim = c ? atomicAdd(&gcnt[t], c) : 0;
    delta[t] = t * CAP + claim - ex;
    cursor[t] = ex;
    __syncthreads();
    // scatter into LDS (sorted by bucket), remember bucket id
    if (f) {
        const long long* p = (const long long*)ei;
        for (long long i = s + t; i < e; i += 512) {
            int sval = (int)p[i], dv = (int)p[E + i];
            int b = dv >> 9;
            int pos = atomicAdd(&cursor[b], 1);
            sv[pos] = ((unsigned)sval << 9) | (unsigned)(dv & 511);
            sb[pos] = (unsigned short)b;
        }
    } else {
        const int* p = (const int*)ei;
        for (long long i = s + t; i < e; i += 512) {
            int sval = p[i], dv = p[E + i];
            int b = dv >> 9;
            int pos = atomicAdd(&cursor[b], 1);
            sv[pos] = ((unsigned)sval << 9) | (unsigned)(dv & 511);
            sb[pos] = (unsigned short)b;
        }
    }
    __syncthreads();
    // linear copy-out (consecutive threads -> consecutive addresses)
    int total = s_total;
    for (int i = t; i < total; i += 512)
        binned[delta[sb[i]] + i] = sv[i];
}

// Per-bucket counting sort by local node, scattering csr DIRECTLY to the
// block-owned global region. 1024 threads; shuffle scan over 512 counters.
// Also iptr2, dinv, p1 = x*dinv.
__global__ __launch_bounds__(1024) void k_bucket_csr(
        const unsigned* binned, const int* gcnt, const float* x, int2* iptr2,
        float* dinv, float2* p1, int* csr, int n) {
    __shared__ int cur[512];
    __shared__ int wsum[16];
    int t = threadIdx.x, b = blockIdx.x;
    if (t < 512) cur[t] = 0;
    __syncthreads();
    int cnt = gcnt[b];
    const unsigned* bp = binned + (size_t)b * CAP;
    for (int i = t; i < cnt; i += 1024)
        atomicAdd(&cur[bp[i] & 511u], 1);
    __syncthreads();
    int c = (t < 512) ? cur[t] : 0;
    int lane = t & 63, wid = t >> 6;
    int inc = c;
#pragma unroll
    for (int off = 1; off < 64; off <<= 1) {
        int up = __shfl_up(inc, off, 64);
        if (lane >= off) inc += up;
    }
    if (lane == 63) wsum[wid] = inc;
    __syncthreads();
    int base = 0;
    for (int k = 0; k < wid; k++) base += wsum[k];
    int ex = base + inc - c;
    int gbase = b * CAP;
    if (t < 512) {
        cur[t] = gbase + ex;  // global cursor
        int node = b * 512 + t;
        if (node < n) {
            iptr2[node] = make_int2(gbase + ex, gbase + ex + c);
            float dg = (float)(c + 1);  // +1 self loop
            float r = rsqrtf(dg);
            r = r * (1.5f - 0.5f * dg * r * r);  // Newton refine
            dinv[node] = r;
            p1[node] = make_float2(x[2 * node] * r, x[2 * node + 1] * r);
        }
    }
    __syncthreads();
    for (int i = t; i < cnt; i += 1024) {
        unsigned p = bp[i];
        int pos = atomicAdd(&cur[p & 511u], 1);
        csr[pos] = (int)(p >> 9);
    }
}

// Fused: aggx = A_hat x (dim2, x8 unroll, fp64 acc);
// p2 = bf16(relu(aggx@W1+b1)*dinv), 64B rows (32 ushorts, 2 zero pads).
__global__ void k_agg2_l1(const float2* p1, const int2* iptr2, const int* csr,
                          const float* dinv, const float* W1, const float* b1,
                          float2* aggx, unsigned short* p2, int n) {
    int v = blockIdx.x * 256 + threadIdx.x;
    if (v >= n) return;
    float2 a0 = p1[v];
    double dax = a0.x, day = a0.y;
    int2 se = iptr2[v];
    int s = se.x, e = se.y;
    int i = s;
    for (; i + 7 < e; i += 8) {
        int u0 = csr[i], u1 = csr[i + 1], u2 = csr[i + 2], u3 = csr[i + 3];
        int u4 = csr[i + 4], u5 = csr[i + 5], u6 = csr[i + 6], u7 = csr[i + 7];
        float2 q0 = p1[u0], q1 = p1[u1], q2 = p1[u2], q3 = p1[u3];
        float2 q4 = p1[u4], q5 = p1[u5], q6 = p1[u6], q7 = p1[u7];
        dax += ((double)q0.x + q1.x) + ((double)q2.x + q3.x) +
               ((double)q4.x + q5.x) + ((double)q6.x + q7.x);
        day += ((double)q0.y + q1.y) + ((double)q2.y + q3.y) +
               ((double)q4.y + q5.y) + ((double)q6.y + q7.y);
    }
    for (; i < e; i++) {
        float2 q = p1[csr[i]];
        dax += (double)q.x; day += (double)q.y;
    }
    float r = dinv[v];
    float ax = (float)(dax * (double)r), ay = (float)(day * (double)r);
    aggx[v] = make_float2(ax, ay);
    __align__(16) unsigned short ob[32];
#pragma unroll
    for (int j = 0; j < 30; j++)
        ob[j] = f2bf(fmaxf(fmaf(ax, W1[j], fmaf(ay, W1[30 + j], b1[j])), 0.f) * r);
    ob[30] = 0; ob[31] = 0;
    uint4* d4 = (uint4*)(p2 + (size_t)v * 32);
    const uint4* s4 = (const uint4*)ob;
#pragma unroll
    for (int k = 0; k < 4; k++) d4[k] = s4[k];
}

// Dim-30 aggregation: 8-lane group per node, each lane a uint2 (4 bf16,
// 64B/row/group), x8-unrolled independent gathers, fp64 accumulators.
__global__ void k_agg30(const uint2* p2u, const int2* iptr2,
                        const int* csr, const float* dinv,
                        uint2* agghu, int n) {
    int t = threadIdx.x;
    int g = blockIdx.x * 32 + (t >> 3);
    int l = t & 7;
    if (g >= n) return;
    uint2 w = p2u[(size_t)g * 8 + l];  // self loop (pads zero)
    double a0 = (double)bf2f((unsigned short)(w.x & 0xFFFFu));
    double a1 = (double)bf2f((unsigned short)(w.x >> 16));
    double a2 = (double)bf2f((unsigned short)(w.y & 0xFFFFu));
    double a3 = (double)bf2f((unsigned short)(w.y >> 16));
    int2 se = iptr2[g];
    int s = se.x, e = se.y;
    int i = s;
    for (; i + 7 < e; i += 8) {
        int u0 = csr[i], u1 = csr[i + 1], u2 = csr[i + 2], u3 = csr[i + 3];
        int u4 = csr[i + 4], u5 = csr[i + 5], u6 = csr[i + 6], u7 = csr[i + 7];
        uint2 w0 = p2u[(size_t)u0 * 8 + l];
        uint2 w1 = p2u[(size_t)u1 * 8 + l];
        uint2 w2 = p2u[(size_t)u2 * 8 + l];
        uint2 w3 = p2u[(size_t)u3 * 8 + l];
        uint2 w4 = p2u[(size_t)u4 * 8 + l];
        uint2 w5 = p2u[(size_t)u5 * 8 + l];
        uint2 w6 = p2u[(size_t)u6 * 8 + l];
        uint2 w7 = p2u[(size_t)u7 * 8 + l];
        a0 += ((double)bf2f((unsigned short)(w0.x & 0xFFFFu)) + bf2f((unsigned short)(w1.x & 0xFFFFu))) +
              ((double)bf2f((unsigned short)(w2.x & 0xFFFFu)) + bf2f((unsigned short)(w3.x & 0xFFFFu))) +
              ((double)bf2f((unsigned short)(w4.x & 0xFFFFu)) + bf2f((unsigned short)(w5.x & 0xFFFFu))) +
              ((double)bf2f((unsigned short)(w6.x & 0xFFFFu)) + bf2f((unsigned short)(w7.x & 0xFFFFu)));
        a1 += ((double)bf2f((unsigned short)(w0.x >> 16)) + bf2f((unsigned short)(w1.x >> 16))) +
              ((double)bf2f((unsigned short)(w2.x >> 16)) + bf2f((unsigned short)(w3.x >> 16))) +
              ((double)bf2f((unsigned short)(w4.x >> 16)) + bf2f((unsigned short)(w5.x >> 16))) +
              ((double)bf2f((unsigned short)(w6.x >> 16)) + bf2f((unsigned short)(w7.x >> 16)));
        a2 += ((double)bf2f((unsigned short)(w0.y & 0xFFFFu)) + bf2f((unsigned short)(w1.y & 0xFFFFu))) +
              ((double)bf2f((unsigned short)(w2.y & 0xFFFFu)) + bf2f((unsigned short)(w3.y & 0xFFFFu))) +
              ((double)bf2f((unsigned short)(w4.y & 0xFFFFu)) + bf2f((unsigned short)(w5.y & 0xFFFFu))) +
              ((double)bf2f((unsigned short)(w6.y & 0xFFFFu)) + bf2f((unsigned short)(w7.y & 0xFFFFu)));
        a3 += ((double)bf2f((unsigned short)(w0.y >> 16)) + bf2f((unsigned short)(w1.y >> 16))) +
              ((double)bf2f((unsigned short)(w2.y >> 16)) + bf2f((unsigned short)(w3.y >> 16))) +
              ((double)bf2f((unsigned short)(w4.y >> 16)) + bf2f((unsigned short)(w5.y >> 16))) +
              ((double)bf2f((unsigned short)(w6.y >> 16)) + bf2f((unsigned short)(w7.y >> 16)));
    }
    for (; i < e; i++) {
        uint2 wv = p2u[(size_t)csr[i] * 8 + l];
        a0 += (double)bf2f((unsigned short)(wv.x & 0xFFFFu));
        a1 += (double)bf2f((unsigned short)(wv.x >> 16));
        a2 += (double)bf2f((unsigned short)(wv.y & 0xFFFFu));
        a3 += (double)bf2f((unsigned short)(wv.y >> 16));
    }
    double r = (double)dinv[g];
    uint2 o;
    o.x = (unsigned)f2bf((float)(a0 * r)) | ((unsigned)f2bf((float)(a1 * r)) << 16);
    o.y = (unsigned)f2bf((float)(a2 * r)) | ((unsigned)f2bf((float)(a3 * r)) << 16);
    agghu[(size_t)g * 8 + l] = o;  // pads (cols 30,31) are zero-sums -> stay 0
}

// h2 = relu((Ah1)W2[:30] + (Ax)W2[30:] + b2); p3 = ([h2,x]@W3) * dinv.
// Block stages its 256 bf16 aggh rows through LDS (stride-17 uints).
__global__ void k_layer2(const unsigned short* aggh, const float2* aggx,
                         const float* x, const float* W2, const float* W3,
                         const float* b2, const float* dinv, float* p3, int n) {
    __shared__ float W2s[32 * 30];
    __shared__ float W3s[32];
    __shared__ float b2s[30];
    __shared__ unsigned hsh[256 * 17];
    int t = threadIdx.x;
    for (int i = t; i < 960; i += 256) W2s[i] = W2[i];
    if (t < 32) W3s[t] = W3[t];
    if (t < 30) b2s[t] = b2[t];
    const unsigned* ag = (const unsigned*)aggh + (size_t)blockIdx.x * 256 * 16;
    int rows = min(256, n - blockIdx.x * 256);
    for (int i = t; i < rows * 16; i += 256) {
        int rr = i >> 4, cc = i & 15;
        hsh[rr * 17 + cc] = ag[i];
    }
    __syncthreads();
    int v = blockIdx.x * 256 + t;
    if (v >= n) return;
    float2 a = aggx[v];
    float acc[30];
#pragma unroll
    for (int j = 0; j < 30; j++)
        acc[j] = fmaf(a.x, W2s[30 * 30 + j], fmaf(a.y, W2s[31 * 30 + j], b2s[j]));
#pragma unroll
    for (int kk = 0; kk < 15; kk++) {  // 30 values = 15 uint pairs
        unsigned pr = hsh[t * 17 + kk];
        float h0 = bf2f((unsigned short)(pr & 0xFFFFu));
        float h1v = bf2f((unsigned short)(pr >> 16));
#pragma unroll
        for (int j = 0; j < 30; j++)
            acc[j] = fmaf(h0, W2s[(2 * kk) * 30 + j], acc[j]);
#pragma unroll
        for (int j = 0; j < 30; j++)
            acc[j] = fmaf(h1v, W2s[(2 * kk + 1) * 30 + j], acc[j]);
    }
    float s3 = 0.f;
#pragma unroll
    for (int j = 0; j < 30; j++) s3 = fmaf(fmaxf(acc[j], 0.f), W3s[j], s3);
    s3 = fmaf(x[2 * v], W3s[30], s3);
    s3 = fmaf(x[2 * v + 1], W3s[31], s3);
    p3[v] = s3 * dinv[v];
}

// out_v = dinv_v * (p3_v + sum p3_u) + b3   (dim 1, x8 unroll, fp64 acc)
__global__ void k_agg1(const float* p3, const int2* iptr2, const int* csr,
                       const float* dinv, const float* b3, float* out, int n) {
    int v = blockIdx.x * 256 + threadIdx.x;
    if (v >= n) return;
    double acc = (double)p3[v];
    int2 se = iptr2[v];
    int s = se.x, e = se.y;
    int i = s;
    for (; i + 7 < e; i += 8) {
        int u0 = csr[i], u1 = csr[i + 1], u2 = csr[i + 2], u3 = csr[i + 3];
        int u4 = csr[i + 4], u5 = csr[i + 5], u6 = csr[i + 6], u7 = csr[i + 7];
        float f0 = p3[u0], f1 = p3[u1], f2 = p3[u2], f3 = p3[u3];
        float f4 = p3[u4], f5 = p3[u5], f6 = p3[u6], f7 = p3[u7];
        acc += ((double)f0 + f1) + ((double)f2 + f3) +
               ((double)f4 + f5) + ((double)f6 + f7);
    }
    for (; i < e; i++) acc += (double)p3[csr[i]];
    out[v] = (float)(acc * (double)dinv[v] + (double)b3[0]);
}

extern "C" void kernel_launch(void* const* d_in, const int* in_sizes, int n_in,
                              void* d_out, int out_size, void* d_ws, size_t ws_size,
                              hipStream_t stream) {
    const float* x  = (const float*)d_in[0];
    const void*  ei = d_in[1];
    const float* W1 = (const float*)d_in[2];
    const float* b1 = (const float*)d_in[3];
    const float* W2 = (const float*)d_in[4];
    const float* b2 = (const float*)d_in[5];
    const float* W3 = (const float*)d_in[6];
    const float* b3 = (const float*)d_in[7];
    float* out = (float*)d_out;
    const int n = in_sizes[0] / 2;
    const long long E = in_sizes[1] / 2;
    const int B = (n + 511) / 512;  // dst buckets of 512 nodes (<=512 buckets)

    char* w = (char*)d_ws;
    auto alloc = [&](size_t b) { void* p = (void*)w; w += (b + 255) & ~(size_t)255; return p; };
    int*            gcnt   = (int*)alloc(512 * 4);
    unsigned*       binned = (unsigned*)alloc((size_t)B * CAP * 4);
    int*            csr    = (int*)alloc((size_t)B * CAP * 4);
    int2*           iptr2  = (int2*)alloc((size_t)n * 8);
    float*          dinv   = (float*)alloc((size_t)n * 4);
    float2*         p1     = (float2*)alloc((size_t)n * 8);
    float2*         aggx   = (float2*)alloc((size_t)n * 8);
    unsigned short* p2     = (unsigned short*)alloc((size_t)n * 32 * 2);
    unsigned short* aggh   = (unsigned short*)alloc((size_t)n * 32 * 2);
    float*          p3     = (float*)alloc((size_t)n * 4);

    int nblocks = (n + 255) / 256;
    int nbin = (int)((E + CHUNK - 1) / CHUNK);

    hipMemsetAsync(gcnt, 0, 512 * 4, stream);
    k_bin<<<nbin, 512, 0, stream>>>(ei, E, gcnt, binned, B);
    k_bucket_csr<<<B, 1024, 0, stream>>>(binned, gcnt, x, iptr2, dinv, p1, csr, n);
    k_agg2_l1<<<nblocks, 256, 0, stream>>>(p1, iptr2, csr, dinv, W1, b1, aggx, p2, n);
    k_agg30<<<(n + 31) / 32, 256, 0, stream>>>((const uint2*)p2, iptr2, csr, dinv,
                                               (uint2*)aggh, n);
    k_layer2<<<nblocks, 256, 0, stream>>>(aggh, aggx, x, W2, W3, b2, dinv, p3, n);
    k_agg1<<<nblocks, 256, 0, stream>>>(p3, iptr2, csr, dinv, b3, out, n);
}